// Round 4
// baseline (374.518 us; speedup 1.0000x reference)
//
#include <hip/hip_runtime.h>

// ---------------------------------------------------------------------------
// GSNet forward, live subgraph only (hk branch dead in reference).
// B=4, N=50000, T=12, HID=32, C=64, R=64.
// Round-4: k_out redesigned lane=node (no cross-lane, no LDS, weights via
// s_load). qp transposed by k_tr. E_kv atomics replaced by partials + k_red.
// ---------------------------------------------------------------------------

#define NN    50000
#define QS    50048               // padded qpT row stride
#define EPSP  1e-4f
#define NRM   0.42044820762685725f   // 32^-0.25
#define HNRM2 0.08838834764831843f   // 0.5 * 32^-0.5

#define DEV __device__ __forceinline__

DEV float bcast(float v, int lane) {
  return __int_as_float(__builtin_amdgcn_readlane(__float_as_int(v), lane));
}
template<int CTRL>
DEV float dpp_add(float x) {
  int p = __builtin_amdgcn_update_dpp(0, __float_as_int(x), CTRL, 0xF, 0xF, false);
  return x + __int_as_float(p);
}
template<int CTRL>
DEV float dpp_max(float x) {
  int p = __builtin_amdgcn_update_dpp(0, __float_as_int(x), CTRL, 0xF, 0xF, false);
  return fmaxf(x, __int_as_float(p));
}
DEV float wave_max(float x) {
  x = dpp_max<0xB1>(x); x = dpp_max<0x4E>(x);
  x = dpp_max<0x141>(x); x = dpp_max<0x140>(x);
  return fmaxf(fmaxf(bcast(x, 0), bcast(x, 16)),
               fmaxf(bcast(x, 32), bcast(x, 48)));
}
DEV unsigned fenc(float f) {
  int i = __float_as_int(f);
  return (unsigned)(i ^ ((i >> 31) | 0x80000000));
}
DEV float fdec(unsigned u) {
  int i = (u & 0x80000000u) ? (int)(u ^ 0x80000000u) : ~(int)u;
  return __int_as_float(i);
}

// ---------------------------------------------------------------------------
// k_weff: Weff[c][t] = fcA[c]@W_in[:,t];  beff[c] = fcA@b_in + fc_b
// ---------------------------------------------------------------------------
__global__ void k_weff(const float* __restrict__ fc_w,
                       const float* __restrict__ w_input,
                       const float* __restrict__ b_input,
                       const float* __restrict__ fc_b,
                       float* __restrict__ Weff, float* __restrict__ beff)
{
  const int c = threadIdx.x;  // 64 threads
  float fr[32];
  #pragma unroll
  for (int d = 0; d < 32; ++d) fr[d] = fc_w[c * 64 + d];
  #pragma unroll
  for (int t = 0; t < 12; ++t) {
    float s = 0.f;
    #pragma unroll
    for (int d = 0; d < 32; ++d) s = fmaf(fr[d], w_input[d * 12 + t], s);
    Weff[c * 12 + t] = s;
  }
  float s = fc_b[c];
  #pragma unroll
  for (int d = 0; d < 32; ++d) s = fmaf(fr[d], b_input[d], s);
  beff[c] = s;
}

// ---------------------------------------------------------------------------
// k_xpack: xp[i] = x[i*3] ; 4 outputs (3 float4 in, 1 float4 out) per thread
// ---------------------------------------------------------------------------
__global__ __launch_bounds__(256) void k_xpack(const float* __restrict__ x,
                                               float* __restrict__ xp)
{
  const int i4 = blockIdx.x * 256 + threadIdx.x;
  if (i4 >= 600000) return;
  const float4* src = (const float4*)(x + (size_t)i4 * 12);
  float4 a = src[0], b = src[1], c = src[2];
  float4 o; o.x = a.x; o.y = a.w; o.z = b.z; o.w = c.y;  // elems 0,3,6,9
  ((float4*)xp)[i4] = o;
}

// ---------------------------------------------------------------------------
// k_node (batch-independent): nv1/nv2 (split halves), g2, qp, ek, eksum, Mmax
// ---------------------------------------------------------------------------
__global__ __launch_bounds__(256) void k_node(
    const float* __restrict__ node_emb,
    const float* __restrict__ w1, const float* __restrict__ b1,
    const float* __restrict__ w2, const float* __restrict__ b2,
    const float* __restrict__ rm1, const float* __restrict__ fc_w,
    const float* __restrict__ beff,
    float* __restrict__ qp_out, float* __restrict__ ek_out,
    float* __restrict__ g2_out,
    float* __restrict__ eksum, unsigned* __restrict__ Mmax)
{
  const int lane = threadIdx.x & 63;
  const int wv = threadIdx.x >> 6;
  const int j = lane & 31;
  const int gw = (blockIdx.x * 256 + threadIdx.x) >> 6;
  const int nw = (gridDim.x * 256) >> 6;

  __shared__ float nvs[4][68];

  float wrow[32], fbr[32], rmr[32];
  const float* wsel = (lane < 32) ? w1 : w2;
  #pragma unroll
  for (int d = 0; d < 32; ++d) {
    wrow[d] = wsel[j * 32 + d];
    fbr[d]  = fc_w[lane * 64 + 32 + d];
    rmr[d]  = rm1[lane * 32 + d];
  }
  const float bsel = (lane < 32) ? b1[j] : b2[j];
  const float be = beff[lane];

  float eks_acc = 0.f, mk_run = -3.0e38f;

  for (int n = gw; n < NN; n += nw) {
    const int nu = __builtin_amdgcn_readfirstlane(n);
    const float4* ne4 = (const float4*)(node_emb + (size_t)nu * 32);
    float nd0[32];
    #pragma unroll
    for (int k = 0; k < 8; ++k) {
      float4 c = ne4[k];
      nd0[4*k] = c.x; nd0[4*k+1] = c.y; nd0[4*k+2] = c.z; nd0[4*k+3] = c.w;
    }
    float a0 = bsel, a1 = 0.f, a2 = 0.f, a3 = 0.f;
    #pragma unroll
    for (int d = 0; d < 32; d += 4) {
      a0 = fmaf(nd0[d],   wrow[d],   a0);
      a1 = fmaf(nd0[d+1], wrow[d+1], a1);
      a2 = fmaf(nd0[d+2], wrow[d+2], a2);
      a3 = fmaf(nd0[d+3], wrow[d+3], a3);
    }
    const float nv = (a0 + a1) + (a2 + a3);
    float g0 = be, g1 = 0.f, g2a = 0.f, g3 = 0.f;
    #pragma unroll
    for (int d = 0; d < 32; d += 4) {
      g0 = fmaf(nd0[d],   fbr[d],   g0);
      g1 = fmaf(nd0[d+1], fbr[d+1], g1);
      g2a = fmaf(nd0[d+2], fbr[d+2], g2a);
      g3 = fmaf(nd0[d+3], fbr[d+3], g3);
    }
    g2_out[(size_t)nu * 64 + lane] = (g0 + g1) + (g2a + g3);
    float t = nv * nv;
    t = dpp_add<0xB1>(t); t = dpp_add<0x4E>(t);
    t = dpp_add<0x141>(t); t = dpp_add<0x140>(t);
    const float dq = bcast(t, 0) + bcast(t, 16);
    const float dk = bcast(t, 32) + bcast(t, 48);
    nvs[wv][lane] = nv;                    // same-wave RAW
    float q0 = 0.f, q1 = 0.f, k0 = 0.f, k1 = 0.f;
    const float4* nv1p = (const float4*)&nvs[wv][0];
    const float4* nv2p = (const float4*)&nvs[wv][32];
    #pragma unroll
    for (int k = 0; k < 8; ++k) {
      float4 c = nv1p[k];
      q0 = fmaf(c.x, rmr[4*k],   q0); q1 = fmaf(c.y, rmr[4*k+1], q1);
      q0 = fmaf(c.z, rmr[4*k+2], q0); q1 = fmaf(c.w, rmr[4*k+3], q1);
    }
    #pragma unroll
    for (int k = 0; k < 8; ++k) {
      float4 c = nv2p[k];
      k0 = fmaf(c.x, rmr[4*k],   k0); k1 = fmaf(c.y, rmr[4*k+1], k1);
      k0 = fmaf(c.z, rmr[4*k+2], k0); k1 = fmaf(c.w, rmr[4*k+3], k1);
    }
    const float ddq = (q0 + q1) * NRM;
    const float ddk = (k0 + k1) * NRM;
    const float mq = wave_max(ddq);
    const float qpv = __expf(ddq - HNRM2 * dq - mq) + EPSP;
    const float ekv = __expf(ddk - HNRM2 * dk);
    mk_run = fmaxf(mk_run, ddk);
    eks_acc += ekv;
    qp_out[(size_t)nu * 64 + lane] = qpv;
    ek_out[(size_t)nu * 64 + lane] = ekv;
  }
  atomicAdd(&eksum[lane], eks_acc);
  const float mw = wave_max(mk_run);
  if (lane == 0) atomicMax(Mmax, fenc(mw));
}

// ---------------------------------------------------------------------------
// k_tr: qp[N][64] -> qpT[64][QS] via LDS tile (conflict-free, coalesced)
// ---------------------------------------------------------------------------
__global__ __launch_bounds__(256) void k_tr(const float* __restrict__ qp,
                                            float* __restrict__ qpT)
{
  __shared__ float t[64][65];
  const int n0 = blockIdx.x * 64;
  const int c = threadIdx.x & 63;
  const int r4 = threadIdx.x >> 6;
  #pragma unroll
  for (int k = 0; k < 16; ++k) {
    const int row = k * 4 + r4;
    const int n = n0 + row;
    t[row][c] = (n < NN) ? qp[(size_t)n * 64 + c] : 0.f;
  }
  __syncthreads();
  #pragma unroll
  for (int k = 0; k < 16; ++k) {
    const int r = k * 4 + r4;
    const int n = n0 + c;
    if (n < NN) qpT[(size_t)r * QS + n] = t[c][r];
  }
}

// ---------------------------------------------------------------------------
// k_kv: v = relu(Weff@xt + g2[n]); partial E_kv/Vsum per block (no atomics)
// grid 512: b = blk&3, kb = blk>>2 (128 partials per batch)
// ---------------------------------------------------------------------------
__global__ __launch_bounds__(256) void k_kv(
    const float* __restrict__ xp, const float* __restrict__ Weff,
    const float* __restrict__ g2_in, const float* __restrict__ ek_in,
    float* __restrict__ part, float* __restrict__ vpart)
{
  const int lane = threadIdx.x & 63;
  const int wv = threadIdx.x >> 6;
  const int b = blockIdx.x & 3;
  const int kb = blockIdx.x >> 2;
  const int wInB = kb * 4 + wv;
  const int strideB = 512;

  float wrow[12];
  #pragma unroll
  for (int t = 0; t < 12; ++t) wrow[t] = Weff[lane * 12 + t];

  float acc[64];
  #pragma unroll
  for (int r = 0; r < 64; ++r) acc[r] = 0.f;
  float vs = 0.f;

  for (int n = wInB; n < NN; n += strideB) {
    const int nu = __builtin_amdgcn_readfirstlane(n);
    const float4* xp4 = (const float4*)(xp + ((size_t)b * NN + nu) * 12);
    float4 c0 = xp4[0], c1 = xp4[1], c2 = xp4[2];
    float v0 = fmaf(c0.x, wrow[0], g2_in[(size_t)nu * 64 + lane]);
    float v1 = c0.y * wrow[1], v2 = c0.z * wrow[2], v3 = c0.w * wrow[3];
    v0 = fmaf(c1.x, wrow[4], v0); v1 = fmaf(c1.y, wrow[5], v1);
    v2 = fmaf(c1.z, wrow[6], v2); v3 = fmaf(c1.w, wrow[7], v3);
    v0 = fmaf(c2.x, wrow[8], v0); v1 = fmaf(c2.y, wrow[9], v1);
    v2 = fmaf(c2.z, wrow[10], v2); v3 = fmaf(c2.w, wrow[11], v3);
    const float v = fmaxf((v0 + v1) + (v2 + v3), 0.f);
    const float4* ekp = (const float4*)(ek_in + (size_t)nu * 64);
    #pragma unroll
    for (int k = 0; k < 16; ++k) {
      float4 e = ekp[k];
      acc[4*k]   = fmaf(e.x, v, acc[4*k]);
      acc[4*k+1] = fmaf(e.y, v, acc[4*k+1]);
      acc[4*k+2] = fmaf(e.z, v, acc[4*k+2]);
      acc[4*k+3] = fmaf(e.w, v, acc[4*k+3]);
    }
    vs += v;
  }

  __shared__ float pkv[64][65];
  __shared__ float pvs[64];
  if (wv == 0) {
    #pragma unroll
    for (int r = 0; r < 64; ++r) pkv[r][lane] = acc[r];
    pvs[lane] = vs;
  }
  __syncthreads();
  for (int w = 1; w < 4; ++w) {
    if (wv == w) {
      #pragma unroll
      for (int r = 0; r < 64; ++r) pkv[r][lane] += acc[r];
      pvs[lane] += vs;
    }
    __syncthreads();
  }
  const size_t base = (size_t)(b * 128 + kb) * 4096;
  for (int i = threadIdx.x; i < 4096; i += 256)
    part[base + i] = pkv[i >> 6][i & 63];
  if (threadIdx.x < 64) vpart[(b * 128 + kb) * 64 + threadIdx.x] = pvs[threadIdx.x];
}

// ---------------------------------------------------------------------------
// k_red: kvF[b][r][c] = exp(-M)*sum_kb part + eps*sum_kb vpart;  ksF[r]
// ---------------------------------------------------------------------------
__global__ __launch_bounds__(256) void k_red(
    const float* __restrict__ part, const float* __restrict__ vpart,
    const float* __restrict__ eksum, const unsigned* __restrict__ Mmax,
    float* __restrict__ kvF, float* __restrict__ ksF)
{
  const int gid = blockIdx.x * 256 + threadIdx.x;   // < 16384
  const int b = gid >> 12, idx = gid & 4095, c = idx & 63;
  float s1 = 0.f, s2 = 0.f;
  for (int kb = 0; kb < 128; ++kb) {
    s1 += part[(size_t)(b * 128 + kb) * 4096 + idx];
    s2 += vpart[(b * 128 + kb) * 64 + c];
  }
  const float sc = __expf(-fdec(*Mmax));
  kvF[gid] = fmaf(sc, s1, EPSP * s2);
  if (gid < 64) ksF[gid] = fmaf(sc, eksum[gid], EPSP * (float)NN);
}

// ---------------------------------------------------------------------------
// k_out: lane = node. wave = (batch wv, 64-node chunk). No LDS, no cross-lane.
// num via qpT (coalesced b32) x kvF rows (s_load uniform).
// ---------------------------------------------------------------------------
__global__ __launch_bounds__(256) void k_out(
    const float* __restrict__ xp, const float* __restrict__ node_emb,
    const float* __restrict__ w_input, const float* __restrict__ b_input,
    const float* __restrict__ qpT, const float* __restrict__ kvF,
    const float* __restrict__ ksF,
    const float* __restrict__ ln_g, const float* __restrict__ ln_b,
    const float* __restrict__ w_reg, const float* __restrict__ b_reg,
    float* __restrict__ out)
{
  const int lane = threadIdx.x & 63;
  const int bu = __builtin_amdgcn_readfirstlane(threadIdx.x >> 6);
  const int n0 = blockIdx.x * 64;
  const int n  = n0 + lane;
  const bool act = (n < NN);
  const int nld = act ? n : (NN - 1);

  // per-lane node data
  const float4* xp4 = (const float4*)(xp + ((size_t)bu * NN + nld) * 12);
  const float4 X0 = xp4[0], X1 = xp4[1], X2 = xp4[2];
  float nd[32];
  const float4* ne4 = (const float4*)(node_emb + (size_t)nld * 32);
  #pragma unroll
  for (int k = 0; k < 8; ++k) {
    float4 c = ne4[k];
    nd[4*k] = c.x; nd[4*k+1] = c.y; nd[4*k+2] = c.z; nd[4*k+3] = c.w;
  }

  // ie[j] = W_in[j]@xt + b_in[j]  (weights via s_load)
  float ie[32];
  #pragma unroll
  for (int j = 0; j < 32; ++j) {
    float a = fmaf(X0.x, w_input[j*12+0], b_input[j]);
    a = fmaf(X0.y, w_input[j*12+1],  a);
    a = fmaf(X0.z, w_input[j*12+2],  a);
    a = fmaf(X0.w, w_input[j*12+3],  a);
    a = fmaf(X1.x, w_input[j*12+4],  a);
    a = fmaf(X1.y, w_input[j*12+5],  a);
    a = fmaf(X1.z, w_input[j*12+6],  a);
    a = fmaf(X1.w, w_input[j*12+7],  a);
    a = fmaf(X2.x, w_input[j*12+8],  a);
    a = fmaf(X2.y, w_input[j*12+9],  a);
    a = fmaf(X2.z, w_input[j*12+10], a);
    a = fmaf(X2.w, w_input[j*12+11], a);
    ie[j] = a;
  }

  // num[c] = sum_r qp[n][r] * kvF[b][r][c] ; den = sum_r qp[n][r]*ksF[r]
  float acc[64];
  #pragma unroll
  for (int c = 0; c < 64; ++c) acc[c] = 0.f;
  float den = 0.f;
  const float* qr = qpT + n;
  const float* kvb = kvF + (size_t)bu * 4096;
  #pragma unroll 2
  for (int r = 0; r < 64; ++r) {
    const float q = qr[(size_t)r * QS];
    #pragma unroll
    for (int c = 0; c < 64; ++c) acc[c] = fmaf(q, kvb[r * 64 + c], acc[c]);
    den = fmaf(q, ksF[r], den);
  }
  const float rden = 1.f / den;

  // h = num/den + xc ; LN over 64 channels (serial per lane)
  #pragma unroll
  for (int c = 0; c < 64; ++c) {
    const float xcv = (c < 32) ? ie[c] : nd[c & 31];
    acc[c] = fmaf(acc[c], rden, xcv);
  }
  float t0 = 0.f, t1 = 0.f, t2 = 0.f, t3 = 0.f;
  #pragma unroll
  for (int c = 0; c < 64; c += 4) {
    t0 += acc[c]; t1 += acc[c+1]; t2 += acc[c+2]; t3 += acc[c+3];
  }
  const float mean = ((t0 + t1) + (t2 + t3)) * 0.015625f;
  t0 = t1 = t2 = t3 = 0.f;
  #pragma unroll
  for (int c = 0; c < 64; c += 4) {
    float d0 = acc[c] - mean, d1 = acc[c+1] - mean;
    float d2 = acc[c+2] - mean, d3 = acc[c+3] - mean;
    t0 = fmaf(d0, d0, t0); t1 = fmaf(d1, d1, t1);
    t2 = fmaf(d2, d2, t2); t3 = fmaf(d3, d3, t3);
  }
  const float rstd = rsqrtf(((t0 + t1) + (t2 + t3)) * 0.015625f + 1e-5f);
  #pragma unroll
  for (int c = 0; c < 64; ++c) {
    const float hn = fmaf((acc[c] - mean) * rstd, ln_g[c], ln_b[c]);
    acc[c] = fmaxf(hn, 0.f);
  }
  #pragma unroll
  for (int c = 0; c < 32; ++c) {
    ie[c] = fmaxf(ie[c], 0.f);
    nd[c] = fmaxf(nd[c], 0.f);
  }

  // out[o] = b_reg[o] + relu(xc)@wA + relu(hn)@wB   (weights via s_load)
  #pragma unroll 2
  for (int o = 0; o < 12; ++o) {
    float a0 = b_reg[o], a1 = 0.f, a2 = 0.f, a3 = 0.f;
    #pragma unroll
    for (int c = 0; c < 32; c += 2) {
      a0 = fmaf(ie[c],   w_reg[o*128 + c],      a0);
      a1 = fmaf(ie[c+1], w_reg[o*128 + c + 1],  a1);
      a2 = fmaf(nd[c],   w_reg[o*128 + 32 + c], a2);
      a3 = fmaf(nd[c+1], w_reg[o*128 + 33 + c], a3);
    }
    #pragma unroll
    for (int c = 0; c < 64; c += 4) {
      a0 = fmaf(acc[c],   w_reg[o*128 + 64 + c], a0);
      a1 = fmaf(acc[c+1], w_reg[o*128 + 65 + c], a1);
      a2 = fmaf(acc[c+2], w_reg[o*128 + 66 + c], a2);
      a3 = fmaf(acc[c+3], w_reg[o*128 + 67 + c], a3);
    }
    if (act) out[((size_t)bu * NN + n) * 12 + o] = (a0 + a1) + (a2 + a3);
  }
}

// ---------------------------------------------------------------------------
extern "C" void kernel_launch(void* const* d_in, const int* in_sizes, int n_in,
                              void* d_out, int out_size, void* d_ws, size_t ws_size,
                              hipStream_t stream) {
  (void)in_sizes; (void)n_in; (void)out_size; (void)ws_size;
  const float* x       = (const float*)d_in[0];
  const float* node    = (const float*)d_in[1];
  const float* w_input = (const float*)d_in[4];
  const float* b_input = (const float*)d_in[5];
  const float* w1      = (const float*)d_in[6];
  const float* b1      = (const float*)d_in[7];
  const float* w2      = (const float*)d_in[8];
  const float* b2      = (const float*)d_in[9];
  const float* fc_w    = (const float*)d_in[14];
  const float* fc_b    = (const float*)d_in[15];
  const float* ln_g    = (const float*)d_in[18];
  const float* ln_b    = (const float*)d_in[19];
  const float* w_reg   = (const float*)d_in[22];
  const float* b_reg   = (const float*)d_in[23];
  const float* rm1     = (const float*)d_in[24];

  // workspace layout (float offsets):
  float* ws      = (float*)d_ws;
  float* eksum   = ws;                   // 64
  unsigned* Mmax = (unsigned*)(ws + 64); // 1
  float* Weff    = ws + 128;             // 768
  float* beff    = ws + 896;             // 64
  float* kvF     = ws + 960;             // 16384
  float* ksF     = ws + 17344;           // 64
  float* qp      = ws + 17408;           // 3,200,000
  float* ek      = ws + 3217408;         // 3,200,000
  float* g2      = ws + 6417408;         // 3,200,000
  float* xp      = ws + 9617408;         // 2,400,000
  float* qpT     = ws + 12017408;        // 64*QS = 3,203,072
  float* part    = ws + 15220480;        // 4*128*4096 = 2,097,152
  float* vpart   = ws + 17317632;        // 4*128*64 = 32,768
  // total 17,350,400 floats = 69.4 MB

  hipMemsetAsync(d_ws, 0, 128 * sizeof(float), stream);   // eksum + Mmax
  k_weff<<<1, 64, 0, stream>>>(fc_w, w_input, b_input, fc_b, Weff, beff);
  k_xpack<<<2344, 256, 0, stream>>>(x, xp);
  k_node<<<512, 256, 0, stream>>>(node, w1, b1, w2, b2, rm1, fc_w, beff,
                                  qp, ek, g2, eksum, Mmax);
  k_tr<<<782, 256, 0, stream>>>(qp, qpT);
  k_kv<<<512, 256, 0, stream>>>(xp, Weff, g2, ek, part, vpart);
  k_red<<<64, 256, 0, stream>>>(part, vpart, eksum, Mmax, kvF, ksF);
  k_out<<<782, 256, 0, stream>>>(xp, node, w_input, b_input, qpT, kvF, ksF,
                                 ln_g, ln_b, w_reg, b_reg, (float*)d_out);
}